// Round 1
// baseline (1174.008 us; speedup 1.0000x reference)
//
#include <hip/hip_runtime.h>

typedef _Float16 f16;
typedef f16 f16x8 __attribute__((ext_vector_type(8)));
typedef f16 f16x4 __attribute__((ext_vector_type(4)));
typedef float f32x4 __attribute__((ext_vector_type(4)));

#define B_ 4
#define T_ 512
#define DM_ 768
#define H_ 8
#define DQ_ 32
#define FF_ 3072
#define L_ 6
#define OUT_ 80
#define M_ (B_*T_)   // 2048 tokens

// ---------------- conversion / packing kernels (run every launch; ws is poisoned) ----------------

__global__ void cast4_kernel(const float* __restrict__ in, f16* __restrict__ out, int n4) {
    int id = blockIdx.x * 256 + threadIdx.x;
    if (id < n4) {
        const float4 v = ((const float4*)in)[id];
        f16x4 o; o[0] = (f16)v.x; o[1] = (f16)v.y; o[2] = (f16)v.z; o[3] = (f16)v.w;
        ((f16x4*)out)[id] = o;
    }
}

// BTqkv[l][n][k], n in [0,768): n<256 -> wq (scaled by 1/sqrt(32)), 256..511 -> wk, 512..767 -> wv
// weight layout (L,H,DM,DQ); out column n = h*32 + a
__global__ void pack_qkv_kernel(const float* __restrict__ wq, const float* __restrict__ wk,
                                const float* __restrict__ wv, f16* __restrict__ out) {
    long id = (long)blockIdx.x * 256 + threadIdx.x;
    if (id >= (long)L_ * 768 * 768) return;
    int k = (int)(id % 768);
    long t = id / 768;
    int n = (int)(t % 768);
    int l = (int)(t / 768);
    int sec = n >> 8; int nn = n & 255; int h = nn >> 5; int a = nn & 31;
    const float* w = (sec == 0) ? wq : (sec == 1 ? wk : wv);
    float v = w[(((long)l * H_ + h) * DM_ + k) * DQ_ + a];
    if (sec == 0) v *= 0.17677669529663687f;   // 1/sqrt(DQ) folded into q weights
    out[id] = (f16)v;
}

// BTwo[l][n=dm][k=f], f = h*32+a ; wo layout (L,H,DQ,DM)
__global__ void pack_wo_kernel(const float* __restrict__ wo, f16* __restrict__ out) {
    long id = (long)blockIdx.x * 256 + threadIdx.x;
    if (id >= (long)L_ * 768 * 256) return;
    int k = (int)(id % 256);
    long t = id / 256;
    int n = (int)(t % 768);
    int l = (int)(t / 768);
    int h = k >> 5, a = k & 31;
    out[id] = (f16)wo[(((long)l * H_ + h) * DQ_ + a) * DM_ + n];
}

// ---------------- GEMM: C[M,N] = A[M,K] @ Bt[N,K]^T, f16 in, fp32 acc ----------------
// mode bits: 1=+bias[col], 2=+res[row,col] (fp32), 4=ReLU, 8=write outF(fp32), 16=write outH(f16)
// BM=64, BN=128, BK=32. 4 waves (2x2), each wave 32x64 via 2x4 frags of 16x16x32 MFMA.

__global__ __launch_bounds__(256) void gemm_kernel(
    const f16* __restrict__ A, const f16* __restrict__ Bt,
    const float* __restrict__ bias, const float* __restrict__ res,
    float* __restrict__ outF, f16* __restrict__ outH,
    int M, int N, int K, int mode)
{
    __shared__ __align__(16) f16 As[64 * 40];    // +8 f16 pad per row for bank spread
    __shared__ __align__(16) f16 Bs[128 * 40];
    const int tid = threadIdx.x;
    const int m0 = blockIdx.y * 64, n0 = blockIdx.x * 128;
    const int wave = tid >> 6, lane = tid & 63;
    const int wr = wave >> 1, wc = wave & 1;
    const int l15 = lane & 15, l4 = lane >> 4;
    const int sr = tid >> 2, sc = (tid & 3) * 8;

    const f16* Ap  = A  + (long)(m0 + sr) * K + sc;
    const f16* Bp0 = Bt + (long)(n0 + sr) * K + sc;
    const f16* Bp1 = Bt + (long)(n0 + sr + 64) * K + sc;

    f32x4 acc[2][4];
#pragma unroll
    for (int i = 0; i < 2; ++i)
#pragma unroll
        for (int j = 0; j < 4; ++j) acc[i][j] = (f32x4){0.f, 0.f, 0.f, 0.f};

    uint4 av  = *(const uint4*)Ap;
    uint4 bv0 = *(const uint4*)Bp0;
    uint4 bv1 = *(const uint4*)Bp1;

    for (int k0 = 0; k0 < K; k0 += 32) {
        *(uint4*)(&As[sr * 40 + sc])        = av;
        *(uint4*)(&Bs[sr * 40 + sc])        = bv0;
        *(uint4*)(&Bs[(sr + 64) * 40 + sc]) = bv1;
        __syncthreads();
        if (k0 + 32 < K) {   // prefetch next tile into regs; overlaps with MFMA below
            av  = *(const uint4*)(Ap  + k0 + 32);
            bv0 = *(const uint4*)(Bp0 + k0 + 32);
            bv1 = *(const uint4*)(Bp1 + k0 + 32);
        }
        f16x8 af[2], bf[4];
#pragma unroll
        for (int i = 0; i < 2; ++i)
            af[i] = *(const f16x8*)(&As[(wr * 32 + i * 16 + l15) * 40 + l4 * 8]);
#pragma unroll
        for (int j = 0; j < 4; ++j)
            bf[j] = *(const f16x8*)(&Bs[(wc * 64 + j * 16 + l15) * 40 + l4 * 8]);
#pragma unroll
        for (int i = 0; i < 2; ++i)
#pragma unroll
            for (int j = 0; j < 4; ++j)
                acc[i][j] = __builtin_amdgcn_mfma_f32_16x16x32_f16(af[i], bf[j], acc[i][j], 0, 0, 0);
        __syncthreads();
    }

#pragma unroll
    for (int i = 0; i < 2; ++i) {
#pragma unroll
        for (int j = 0; j < 4; ++j) {
            const int col = n0 + wc * 64 + j * 16 + l15;
            const float bv = (mode & 1) ? bias[col] : 0.f;
#pragma unroll
            for (int r = 0; r < 4; ++r) {
                const int row = m0 + wr * 32 + i * 16 + l4 * 4 + r;
                float v = acc[i][j][r] + bv;
                if (mode & 2) v += res[(long)row * N + col];
                if (mode & 4) v = fmaxf(v, 0.f);
                if (mode & 8)  outF[(long)row * N + col] = v;
                if (mode & 16) outH[(long)row * N + col] = (f16)v;
            }
        }
    }
}

// ---------------- banded attention (fp32). qkv rows: [q(256) | k(256) | v(256)] ----------------
// band: pos finite only for |k-q| <= 99 (pad=412 case of the reference); out-of-band prob == 0 exactly.
// grid (8 qtiles, 8 heads, 4 batch); block 256 = 64 q-rows x 4 threads.

__global__ __launch_bounds__(256) void attn_kernel(
    const float* __restrict__ qkv, const float* __restrict__ rel_all,
    int l, f16* __restrict__ o)
{
    __shared__ float4 Kw[262][9];   // key window, padded row (144B) for bank spread
    __shared__ float4 Vw[262][9];
    __shared__ float  Pr[64][201];  // scores -> probs, odd stride
    const int tid = threadIdx.x;
    const int qb = blockIdx.x, h = blockIdx.y, b = blockIdx.z;
    const int q0 = qb * 64;
    const int lo = max(0, q0 - 99);
    const int hi = min(512, q0 + 163);
    const int nk = hi - lo;

    const float* kbase = qkv + ((long)(b * T_ + lo)) * 768 + 256 + h * 32;
    const float* vbase = kbase + 256;
    for (int idx = tid; idx < nk * 8; idx += 256) {
        int r = idx >> 3, c = idx & 7;
        Kw[r][c] = *(const float4*)(kbase + (long)r * 768 + c * 4);
        Vw[r][c] = *(const float4*)(vbase + (long)r * 768 + c * 4);
    }
    const int ql = tid >> 2, j = tid & 3;
    const int q = q0 + ql;
    const float* qrow = qkv + ((long)(b * T_ + q)) * 768 + h * 32;
    float4 qv[8];
#pragma unroll
    for (int c = 0; c < 8; ++c) qv[c] = *(const float4*)(qrow + c * 4);
    const float* relh = rel_all + ((long)l * H_ + h) * 199 * 32;
    __syncthreads();

    const int dlo = max(0, 99 - q), dhi = min(199, 611 - q);
    float mx = -1e30f;
    for (int d = j; d < 199; d += 4) {
        float s = -1e30f;
        if (d >= dlo && d < dhi) {
            const int kk = q + d - 99 - lo;
            const float* rr = relh + d * 32;
            float4 a4 = {0.f, 0.f, 0.f, 0.f};
#pragma unroll
            for (int c = 0; c < 8; ++c) {
                float4 kv = Kw[kk][c];
                float4 rv = *(const float4*)(rr + c * 4);
                a4.x += qv[c].x * (kv.x + rv.x);   // q·k + q·rel == q·(k+rel)
                a4.y += qv[c].y * (kv.y + rv.y);
                a4.z += qv[c].z * (kv.z + rv.z);
                a4.w += qv[c].w * (kv.w + rv.w);
            }
            s = a4.x + a4.y + a4.z + a4.w;
            mx = fmaxf(mx, s);
        }
        Pr[ql][d] = s;
    }
    mx = fmaxf(mx, __shfl_xor(mx, 1));
    mx = fmaxf(mx, __shfl_xor(mx, 2));
    float sum = 0.f;
    for (int d = j; d < 199; d += 4) {
        float e = __expf(Pr[ql][d] - mx);   // -1e30 -> exp underflows to 0
        sum += e;
        Pr[ql][d] = e;
    }
    sum += __shfl_xor(sum, 1);
    sum += __shfl_xor(sum, 2);
    const float inv = 1.f / sum;
    __syncthreads();

    float4 o0 = {0.f,0.f,0.f,0.f}, o1 = {0.f,0.f,0.f,0.f};
    for (int d = dlo; d < dhi; ++d) {
        const float p = Pr[ql][d];
        const int kk = q + d - 99 - lo;
        const float4 v0 = Vw[kk][j * 2];
        const float4 v1 = Vw[kk][j * 2 + 1];
        o0.x += p * v0.x; o0.y += p * v0.y; o0.z += p * v0.z; o0.w += p * v0.w;
        o1.x += p * v1.x; o1.y += p * v1.y; o1.z += p * v1.z; o1.w += p * v1.w;
    }
    f16x8 ov;
    ov[0] = (f16)(o0.x * inv); ov[1] = (f16)(o0.y * inv);
    ov[2] = (f16)(o0.z * inv); ov[3] = (f16)(o0.w * inv);
    ov[4] = (f16)(o1.x * inv); ov[5] = (f16)(o1.y * inv);
    ov[6] = (f16)(o1.z * inv); ov[7] = (f16)(o1.w * inv);
    // o layout (b, t, h*32+a) so attn-out GEMM consumes it directly
    *(f16x8*)(o + ((long)(b * T_ + q)) * 256 + h * 32 + j * 8) = ov;
}

// ---------------- LayerNorm over 768, writes fp32 (residual) + f16 (next GEMM A) ----------------

__global__ __launch_bounds__(256) void ln_kernel(
    const float* __restrict__ src, const float* __restrict__ w, const float* __restrict__ bb,
    float* __restrict__ outF, f16* __restrict__ outH)
{
    __shared__ float red1[4], red2[4];
    const int row = blockIdx.x, tid = threadIdx.x;
    const float* x = src + (long)row * 768;
    float v0 = x[tid], v1 = x[tid + 256], v2 = x[tid + 512];
    float s = v0 + v1 + v2;
#pragma unroll
    for (int off = 32; off > 0; off >>= 1) s += __shfl_xor(s, off);
    if ((tid & 63) == 0) red1[tid >> 6] = s;
    __syncthreads();
    const float mu = (red1[0] + red1[1] + red1[2] + red1[3]) * (1.f / 768.f);
    const float d0 = v0 - mu, d1 = v1 - mu, d2 = v2 - mu;
    float ss = d0 * d0 + d1 * d1 + d2 * d2;
#pragma unroll
    for (int off = 32; off > 0; off >>= 1) ss += __shfl_xor(ss, off);
    if ((tid & 63) == 0) red2[tid >> 6] = ss;
    __syncthreads();
    const float var = (red2[0] + red2[1] + red2[2] + red2[3]) * (1.f / 768.f);
    const float inv = rsqrtf(var + 1e-5f);
    float y0 = d0 * inv * w[tid]       + bb[tid];
    float y1 = d1 * inv * w[tid + 256] + bb[tid + 256];
    float y2 = d2 * inv * w[tid + 512] + bb[tid + 512];
    long base = (long)row * 768;
    outF[base + tid] = y0; outF[base + tid + 256] = y1; outF[base + tid + 512] = y2;
    outH[base + tid] = (f16)y0; outH[base + tid + 256] = (f16)y1; outH[base + tid + 512] = (f16)y2;
}

// ---------------- final projection: out[2048,80] = h @ w_out^T + b_out (fp32) ----------------

__global__ __launch_bounds__(128) void final_kernel(
    const float* __restrict__ h, const float* __restrict__ wout,
    const float* __restrict__ bout, float* __restrict__ out)
{
    __shared__ float ls[768];
    const int row = blockIdx.x;
    for (int c = threadIdx.x; c < 768; c += 128) ls[c] = h[(long)row * 768 + c];
    __syncthreads();
    const int c = threadIdx.x;
    if (c < OUT_) {
        const float* wr = wout + (long)c * 768;
        float4 a4 = {0.f, 0.f, 0.f, 0.f};
        for (int k = 0; k < 768; k += 4) {
            float4 wv = *(const float4*)(wr + k);
            a4.x += ls[k]     * wv.x;
            a4.y += ls[k + 1] * wv.y;
            a4.z += ls[k + 2] * wv.z;
            a4.w += ls[k + 3] * wv.w;
        }
        out[(long)row * OUT_ + c] = bout[c] + a4.x + a4.y + a4.z + a4.w;
    }
}

// ---------------- host ----------------

extern "C" void kernel_launch(void* const* d_in, const int* in_sizes, int n_in,
                              void* d_out, int out_size, void* d_ws, size_t ws_size,
                              hipStream_t stream) {
    const float* x     = (const float*)d_in[0];
    const float* wq    = (const float*)d_in[1];
    const float* wk    = (const float*)d_in[2];
    const float* wv    = (const float*)d_in[3];
    const float* wo    = (const float*)d_in[4];
    const float* rel   = (const float*)d_in[5];
    const float* lin1w = (const float*)d_in[6];
    const float* lin1b = (const float*)d_in[7];
    const float* lin2w = (const float*)d_in[8];
    const float* lin2b = (const float*)d_in[9];
    const float* ln1w  = (const float*)d_in[10];
    const float* ln1b  = (const float*)d_in[11];
    const float* ln2w  = (const float*)d_in[12];
    const float* ln2b  = (const float*)d_in[13];
    const float* wout  = (const float*)d_in[14];
    const float* bout  = (const float*)d_in[15];

    char* base = (char*)d_ws;
    size_t off = 0;
    auto alloc = [&](size_t bytes) {
        void* p = base + off;
        off = (off + bytes + 255) & ~(size_t)255;
        return p;
    };
    // total ~108 MB of workspace
    f16*   xH    = (f16*)  alloc((size_t)M_ * 768 * 2);
    f16*   BTqkv = (f16*)  alloc((size_t)L_ * 768 * 768 * 2);
    f16*   BTwo  = (f16*)  alloc((size_t)L_ * 768 * 256 * 2);
    f16*   lin1H = (f16*)  alloc((size_t)L_ * 3072 * 768 * 2);
    f16*   lin2H = (f16*)  alloc((size_t)L_ * 768 * 3072 * 2);
    float* scrF  = (float*)alloc((size_t)M_ * 768 * 4);   // qkv -> h1pre -> h2pre (sequentially dead)
    f16*   oH    = (f16*)  alloc((size_t)M_ * 256 * 2);
    float* ln1F  = (float*)alloc((size_t)M_ * 768 * 4);
    f16*   ln1H  = (f16*)  alloc((size_t)M_ * 768 * 2);
    f16*   ffH   = (f16*)  alloc((size_t)M_ * 3072 * 2);
    float* hF    = (float*)alloc((size_t)M_ * 768 * 4);
    f16*   hH    = (f16*)  alloc((size_t)M_ * 768 * 2);
    (void)ws_size; (void)in_sizes; (void)n_in; (void)out_size;

    cast4_kernel<<<(M_ * 768 / 4 + 255) / 256, 256, 0, stream>>>(x, xH, M_ * 768 / 4);
    cast4_kernel<<<(L_ * 3072 * 768 / 4 + 255) / 256, 256, 0, stream>>>(lin1w, lin1H, L_ * 3072 * 768 / 4);
    cast4_kernel<<<(L_ * 768 * 3072 / 4 + 255) / 256, 256, 0, stream>>>(lin2w, lin2H, L_ * 768 * 3072 / 4);
    pack_qkv_kernel<<<(L_ * 768 * 768 + 255) / 256, 256, 0, stream>>>(wq, wk, wv, BTqkv);
    pack_wo_kernel<<<(L_ * 768 * 256 + 255) / 256, 256, 0, stream>>>(wo, BTwo);

    for (int l = 0; l < L_; ++l) {
        const f16*   aIn   = (l == 0) ? xH : hH;
        const float* resIn = (l == 0) ? x  : hF;
        // QKV projection (q pre-scaled in packed weights): scrF = [q|k|v]
        gemm_kernel<<<dim3(768 / 128, M_ / 64), 256, 0, stream>>>(
            aIn, BTqkv + (size_t)l * 768 * 768, nullptr, nullptr, scrF, nullptr,
            M_, 768, 768, 8);
        // banded attention -> oH (b,t,256) f16
        attn_kernel<<<dim3(8, 8, 4), 256, 0, stream>>>(scrF, rel, l, oH);
        // attn output projection + residual -> scrF (h1pre)
        gemm_kernel<<<dim3(768 / 128, M_ / 64), 256, 0, stream>>>(
            oH, BTwo + (size_t)l * 768 * 256, nullptr, resIn, scrF, nullptr,
            M_, 768, 256, 2 | 8);
        ln_kernel<<<M_, 256, 0, stream>>>(scrF, ln1w + l * 768, ln1b + l * 768, ln1F, ln1H);
        // FFN1: ReLU(ln1 @ lin1^T + b1) -> ffH (f16 only)
        gemm_kernel<<<dim3(3072 / 128, M_ / 64), 256, 0, stream>>>(
            ln1H, lin1H + (size_t)l * 3072 * 768, lin1b + l * 3072, nullptr, nullptr, ffH,
            M_, 3072, 768, 1 | 4 | 16);
        // FFN2: ff @ lin2^T + b2 + ln1 residual -> scrF (h2pre)
        gemm_kernel<<<dim3(768 / 128, M_ / 64), 256, 0, stream>>>(
            ffH, lin2H + (size_t)l * 768 * 3072, lin2b + l * 768, ln1F, scrF, nullptr,
            M_, 768, 3072, 1 | 2 | 8);
        ln_kernel<<<M_, 256, 0, stream>>>(scrF, ln2w + l * 768, ln2b + l * 768, hF, hH);
    }
    final_kernel<<<M_, 128, 0, stream>>>(hF, wout, bout, (float*)d_out);
}

// Round 2
// 1168.615 us; speedup vs baseline: 1.0046x; 1.0046x over previous
//
#include <hip/hip_runtime.h>

typedef _Float16 f16;
typedef f16 f16x8 __attribute__((ext_vector_type(8)));
typedef f16 f16x4 __attribute__((ext_vector_type(4)));
typedef float f32x4 __attribute__((ext_vector_type(4)));

#define B_ 4
#define T_ 512
#define DM_ 768
#define H_ 8
#define DQ_ 32
#define FF_ 3072
#define L_ 6
#define OUT_ 80
#define M_ (B_*T_)   // 2048 tokens

// ---------------- conversion / packing kernels (run every launch; ws is poisoned) ----------------

__global__ void cast4_kernel(const float* __restrict__ in, f16* __restrict__ out, int n4) {
    int id = blockIdx.x * 256 + threadIdx.x;
    if (id < n4) {
        const float4 v = ((const float4*)in)[id];
        f16x4 o; o[0] = (f16)v.x; o[1] = (f16)v.y; o[2] = (f16)v.z; o[3] = (f16)v.w;
        ((f16x4*)out)[id] = o;
    }
}

// BTqkv[l][n][k], n in [0,768): n<256 -> wq (scaled), 256..511 -> wk, 512..767 -> wv
__global__ void pack_qkv_kernel(const float* __restrict__ wq, const float* __restrict__ wk,
                                const float* __restrict__ wv, f16* __restrict__ out) {
    long id = (long)blockIdx.x * 256 + threadIdx.x;
    if (id >= (long)L_ * 768 * 768) return;
    int k = (int)(id % 768);
    long t = id / 768;
    int n = (int)(t % 768);
    int l = (int)(t / 768);
    int sec = n >> 8; int nn = n & 255; int h = nn >> 5; int a = nn & 31;
    const float* w = (sec == 0) ? wq : (sec == 1 ? wk : wv);
    float v = w[(((long)l * H_ + h) * DM_ + k) * DQ_ + a];
    if (sec == 0) v *= 0.17677669529663687f;   // 1/sqrt(DQ) folded into q weights
    out[id] = (f16)v;
}

// BTwo[l][n=dm][k=f], f = h*32+a ; wo layout (L,H,DQ,DM)
__global__ void pack_wo_kernel(const float* __restrict__ wo, f16* __restrict__ out) {
    long id = (long)blockIdx.x * 256 + threadIdx.x;
    if (id >= (long)L_ * 768 * 256) return;
    int k = (int)(id % 256);
    long t = id / 256;
    int n = (int)(t % 768);
    int l = (int)(t / 768);
    int h = k >> 5, a = k & 31;
    out[id] = (f16)wo[(((long)l * H_ + h) * DQ_ + a) * DM_ + n];
}

// w_out (80,768) -> f16 zero-padded to (128,768)
__global__ void pack_wout_kernel(const float* __restrict__ wout, f16* __restrict__ out) {
    int id = blockIdx.x * 256 + threadIdx.x;
    if (id >= 128 * 768) return;
    int k = id % 768, n = id / 768;
    out[id] = (n < OUT_) ? (f16)wout[n * 768 + k] : (f16)0;
}

// ---------------- GEMM: C[M,N] = A[M,K] @ Bt[N,K]^T, f16 in, fp32 acc ----------------
// mode bits: 1=+bias[col], 2=+res[row,col] (fp32, stride N), 4=ReLU, 8=write outF, 16=write outH
// BM=64, BN template (64 or 128), BK=32. 4 waves (2x2).

template<int BN>
__global__ __launch_bounds__(256) void gemm_kernel(
    const f16* __restrict__ A, const f16* __restrict__ Bt,
    const float* __restrict__ bias, const float* __restrict__ res,
    float* __restrict__ outF, f16* __restrict__ outH,
    int M, int N, int K, int mode, int ldOut, int nMax)
{
    constexpr int JF = BN / 32;   // frags per wave in N
    constexpr int NB = BN / 64;   // 64-row staging chunks for B
    __shared__ __align__(16) f16 As[64 * 40];
    __shared__ __align__(16) f16 Bs[BN * 40];
    const int tid = threadIdx.x;
    const int m0 = blockIdx.y * 64, n0 = blockIdx.x * BN;
    const int wave = tid >> 6, lane = tid & 63;
    const int wr = wave >> 1, wc = wave & 1;
    const int l15 = lane & 15, l4 = lane >> 4;
    const int sr = tid >> 2, sc = (tid & 3) * 8;

    const f16* Ap = A + (long)(m0 + sr) * K + sc;
    const f16* Bp[NB];
#pragma unroll
    for (int t = 0; t < NB; ++t) Bp[t] = Bt + (long)(n0 + sr + 64 * t) * K + sc;

    f32x4 acc[2][JF];
#pragma unroll
    for (int i = 0; i < 2; ++i)
#pragma unroll
        for (int j = 0; j < JF; ++j) acc[i][j] = (f32x4){0.f, 0.f, 0.f, 0.f};

    uint4 av = *(const uint4*)Ap;
    uint4 bv[NB];
#pragma unroll
    for (int t = 0; t < NB; ++t) bv[t] = *(const uint4*)Bp[t];

    for (int k0 = 0; k0 < K; k0 += 32) {
        *(uint4*)(&As[sr * 40 + sc]) = av;
#pragma unroll
        for (int t = 0; t < NB; ++t) *(uint4*)(&Bs[(sr + 64 * t) * 40 + sc]) = bv[t];
        __syncthreads();
        if (k0 + 32 < K) {
            av = *(const uint4*)(Ap + k0 + 32);
#pragma unroll
            for (int t = 0; t < NB; ++t) bv[t] = *(const uint4*)(Bp[t] + k0 + 32);
        }
        f16x8 af[2], bf[JF];
#pragma unroll
        for (int i = 0; i < 2; ++i)
            af[i] = *(const f16x8*)(&As[(wr * 32 + i * 16 + l15) * 40 + l4 * 8]);
#pragma unroll
        for (int j = 0; j < JF; ++j)
            bf[j] = *(const f16x8*)(&Bs[(wc * (BN / 2) + j * 16 + l15) * 40 + l4 * 8]);
#pragma unroll
        for (int i = 0; i < 2; ++i)
#pragma unroll
            for (int j = 0; j < JF; ++j)
                acc[i][j] = __builtin_amdgcn_mfma_f32_16x16x32_f16(af[i], bf[j], acc[i][j], 0, 0, 0);
        __syncthreads();
    }

#pragma unroll
    for (int i = 0; i < 2; ++i) {
#pragma unroll
        for (int j = 0; j < JF; ++j) {
            const int col = n0 + wc * (BN / 2) + j * 16 + l15;
            if (col < nMax) {
                const float bvv = (mode & 1) ? bias[col] : 0.f;
#pragma unroll
                for (int r = 0; r < 4; ++r) {
                    const int row = m0 + wr * 32 + i * 16 + l4 * 4 + r;
                    float v = acc[i][j][r] + bvv;
                    if (mode & 2) v += res[(long)row * N + col];
                    if (mode & 4) v = fmaxf(v, 0.f);
                    if (mode & 8)  outF[(long)row * ldOut + col] = v;
                    if (mode & 16) outH[(long)row * ldOut + col] = (f16)v;
                }
            }
        }
    }
}

// ---------------- banded attention. qkv rows: [q(256) | k(256) | v(256)] fp32 ----------------
// band: pos finite only for |k-q| <= 99; out-of-band prob == 0 exactly (matches reference).
// grid (8 qtiles, 8 heads, 4 batch); block 512 = 64 q-rows x 8 lanes.

__global__ __launch_bounds__(512) void attn_kernel(
    const float* __restrict__ qkv, const float* __restrict__ rel_all,
    int l, f16* __restrict__ o)
{
    __shared__ float Kw[262][36];   // 37.7 KB, 16B-aligned rows, stride 144B
    __shared__ f16   Vw[262][40];   // 21.0 KB, stride 80B
    const int tid = threadIdx.x;
    const int qb = blockIdx.x, h = blockIdx.y, b = blockIdx.z;
    const int q0 = qb * 64;
    const int lo = max(0, q0 - 99);
    const int hi = min(512, q0 + 163);
    const int nk = hi - lo;

    const float* kbase = qkv + ((long)(b * T_ + lo)) * 768 + 256 + h * 32;
    const float* vbase = kbase + 256;
    for (int idx = tid; idx < nk * 8; idx += 512) {
        int r = idx >> 3, c = idx & 7;
        *(float4*)&Kw[r][c * 4] = *(const float4*)(kbase + (long)r * 768 + c * 4);
    }
    for (int idx = tid; idx < nk * 4; idx += 512) {
        int r = idx >> 2, c = idx & 3;
        float4 a = *(const float4*)(vbase + (long)r * 768 + c * 8);
        float4 d = *(const float4*)(vbase + (long)r * 768 + c * 8 + 4);
        f16x8 vv;
        vv[0] = (f16)a.x; vv[1] = (f16)a.y; vv[2] = (f16)a.z; vv[3] = (f16)a.w;
        vv[4] = (f16)d.x; vv[5] = (f16)d.y; vv[6] = (f16)d.z; vv[7] = (f16)d.w;
        *(f16x8*)&Vw[r][c * 8] = vv;
    }
    const int ql = tid >> 3, j = tid & 7;
    const int q = q0 + ql;
    const float* qrow = qkv + ((long)(b * T_ + q)) * 768 + h * 32;
    float4 qv[8];
#pragma unroll
    for (int c = 0; c < 8; ++c) qv[c] = *(const float4*)(qrow + c * 4);
    const float* relh = rel_all + ((long)l * H_ + h) * 199 * 32;
    __syncthreads();

    const int dlo = max(0, 99 - q), dhi = min(199, 611 - q);
    float s[25];
    float mx = -1e30f;
#pragma unroll
    for (int it = 0; it < 25; ++it) {
        const int d = j + it * 8;
        float sv = -1e30f;
        if (d < 199 && d >= dlo && d < dhi) {
            const int kk = q + d - 99 - lo;
            const float* rr = relh + d * 32;
            const float* kr = &Kw[kk][0];
            float4 a4 = {0.f, 0.f, 0.f, 0.f};
#pragma unroll
            for (int c = 0; c < 8; ++c) {
                float4 kv4 = *(const float4*)(kr + c * 4);
                float4 rv  = *(const float4*)(rr + c * 4);
                a4.x += qv[c].x * (kv4.x + rv.x);   // q·k + q·rel == q·(k+rel)
                a4.y += qv[c].y * (kv4.y + rv.y);
                a4.z += qv[c].z * (kv4.z + rv.z);
                a4.w += qv[c].w * (kv4.w + rv.w);
            }
            sv = a4.x + a4.y + a4.z + a4.w;
            mx = fmaxf(mx, sv);
        }
        s[it] = sv;
    }
    mx = fmaxf(mx, __shfl_xor(mx, 1));
    mx = fmaxf(mx, __shfl_xor(mx, 2));
    mx = fmaxf(mx, __shfl_xor(mx, 4));
    float sum = 0.f;
#pragma unroll
    for (int it = 0; it < 25; ++it) {
        float e = __expf(s[it] - mx);   // invalid slots: exp(-huge) == 0
        sum += e;
        s[it] = e;
    }
    sum += __shfl_xor(sum, 1);
    sum += __shfl_xor(sum, 2);
    sum += __shfl_xor(sum, 4);
    const float inv = 1.f / sum;

    float oa[32];
#pragma unroll
    for (int c = 0; c < 32; ++c) oa[c] = 0.f;
#pragma unroll
    for (int it = 0; it < 25; ++it) {
        const int d = j + it * 8;
        if (d >= dlo && d < dhi) {
            const int kk = q + d - 99 - lo;
            const float p = s[it];
            const f16* vr = &Vw[kk][0];
#pragma unroll
            for (int c = 0; c < 4; ++c) {
                f16x8 vv = *(const f16x8*)(vr + c * 8);
#pragma unroll
                for (int e = 0; e < 8; ++e) oa[c * 8 + e] += p * (float)vv[e];
            }
        }
    }
#pragma unroll
    for (int c = 0; c < 32; ++c) {
        oa[c] += __shfl_xor(oa[c], 1);
        oa[c] += __shfl_xor(oa[c], 2);
        oa[c] += __shfl_xor(oa[c], 4);
    }
    f16x4 ov;
#pragma unroll
    for (int e = 0; e < 4; ++e) ov[e] = (f16)(oa[j * 4 + e] * inv);
    // o layout (b, t, h*32+a) so attn-out GEMM consumes it directly
    *(f16x4*)(o + ((long)(b * T_ + q)) * 256 + h * 32 + j * 4) = ov;
}

// ---------------- LayerNorm over 768, writes fp32 (residual) + f16 (next GEMM A) ----------------

__global__ __launch_bounds__(256) void ln_kernel(
    const float* __restrict__ src, const float* __restrict__ w, const float* __restrict__ bb,
    float* __restrict__ outF, f16* __restrict__ outH)
{
    __shared__ float red1[4], red2[4];
    const int row = blockIdx.x, tid = threadIdx.x;
    const float* x = src + (long)row * 768;
    float v0 = x[tid], v1 = x[tid + 256], v2 = x[tid + 512];
    float s = v0 + v1 + v2;
#pragma unroll
    for (int off = 32; off > 0; off >>= 1) s += __shfl_xor(s, off);
    if ((tid & 63) == 0) red1[tid >> 6] = s;
    __syncthreads();
    const float mu = (red1[0] + red1[1] + red1[2] + red1[3]) * (1.f / 768.f);
    const float d0 = v0 - mu, d1 = v1 - mu, d2 = v2 - mu;
    float ss = d0 * d0 + d1 * d1 + d2 * d2;
#pragma unroll
    for (int off = 32; off > 0; off >>= 1) ss += __shfl_xor(ss, off);
    if ((tid & 63) == 0) red2[tid >> 6] = ss;
    __syncthreads();
    const float var = (red2[0] + red2[1] + red2[2] + red2[3]) * (1.f / 768.f);
    const float inv = rsqrtf(var + 1e-5f);
    float y0 = d0 * inv * w[tid]       + bb[tid];
    float y1 = d1 * inv * w[tid + 256] + bb[tid + 256];
    float y2 = d2 * inv * w[tid + 512] + bb[tid + 512];
    long base = (long)row * 768;
    outF[base + tid] = y0; outF[base + tid + 256] = y1; outF[base + tid + 512] = y2;
    outH[base + tid] = (f16)y0; outH[base + tid + 256] = (f16)y1; outH[base + tid + 512] = (f16)y2;
}

// ---------------- host ----------------

extern "C" void kernel_launch(void* const* d_in, const int* in_sizes, int n_in,
                              void* d_out, int out_size, void* d_ws, size_t ws_size,
                              hipStream_t stream) {
    const float* x     = (const float*)d_in[0];
    const float* wq    = (const float*)d_in[1];
    const float* wk    = (const float*)d_in[2];
    const float* wv    = (const float*)d_in[3];
    const float* wo    = (const float*)d_in[4];
    const float* rel   = (const float*)d_in[5];
    const float* lin1w = (const float*)d_in[6];
    const float* lin1b = (const float*)d_in[7];
    const float* lin2w = (const float*)d_in[8];
    const float* lin2b = (const float*)d_in[9];
    const float* ln1w  = (const float*)d_in[10];
    const float* ln1b  = (const float*)d_in[11];
    const float* ln2w  = (const float*)d_in[12];
    const float* ln2b  = (const float*)d_in[13];
    const float* wout  = (const float*)d_in[14];
    const float* bout  = (const float*)d_in[15];

    char* base = (char*)d_ws;
    size_t off = 0;
    auto alloc = [&](size_t bytes) {
        void* p = base + off;
        off = (off + bytes + 255) & ~(size_t)255;
        return p;
    };
    f16*   xH    = (f16*)  alloc((size_t)M_ * 768 * 2);
    f16*   BTqkv = (f16*)  alloc((size_t)L_ * 768 * 768 * 2);
    f16*   BTwo  = (f16*)  alloc((size_t)L_ * 768 * 256 * 2);
    f16*   lin1H = (f16*)  alloc((size_t)L_ * 3072 * 768 * 2);
    f16*   lin2H = (f16*)  alloc((size_t)L_ * 768 * 3072 * 2);
    f16*   woutH = (f16*)  alloc((size_t)128 * 768 * 2);
    float* scrF  = (float*)alloc((size_t)M_ * 768 * 4);   // qkv -> h1pre -> h2pre (sequentially dead)
    f16*   oH    = (f16*)  alloc((size_t)M_ * 256 * 2);
    float* ln1F  = (float*)alloc((size_t)M_ * 768 * 4);
    f16*   ln1H  = (f16*)  alloc((size_t)M_ * 768 * 2);
    f16*   ffH   = (f16*)  alloc((size_t)M_ * 3072 * 2);
    float* hF    = (float*)alloc((size_t)M_ * 768 * 4);
    f16*   hH    = (f16*)  alloc((size_t)M_ * 768 * 2);
    (void)ws_size; (void)in_sizes; (void)n_in; (void)out_size;

    cast4_kernel<<<(M_ * 768 / 4 + 255) / 256, 256, 0, stream>>>(x, xH, M_ * 768 / 4);
    cast4_kernel<<<(L_ * 3072 * 768 / 4 + 255) / 256, 256, 0, stream>>>(lin1w, lin1H, L_ * 3072 * 768 / 4);
    cast4_kernel<<<(L_ * 768 * 3072 / 4 + 255) / 256, 256, 0, stream>>>(lin2w, lin2H, L_ * 768 * 3072 / 4);
    pack_qkv_kernel<<<(L_ * 768 * 768 + 255) / 256, 256, 0, stream>>>(wq, wk, wv, BTqkv);
    pack_wo_kernel<<<(L_ * 768 * 256 + 255) / 256, 256, 0, stream>>>(wo, BTwo);
    pack_wout_kernel<<<(128 * 768 + 255) / 256, 256, 0, stream>>>(wout, woutH);

    for (int l = 0; l < L_; ++l) {
        const f16*   aIn   = (l == 0) ? xH : hH;
        const float* resIn = (l == 0) ? x  : hF;
        // QKV projection (q pre-scaled in packed weights): scrF = [q|k|v]
        gemm_kernel<64><<<dim3(12, 32), 256, 0, stream>>>(
            aIn, BTqkv + (size_t)l * 768 * 768, nullptr, nullptr, scrF, nullptr,
            M_, 768, 768, 8, 768, 768);
        // banded attention -> oH (b,t,256) f16
        attn_kernel<<<dim3(8, 8, 4), 512, 0, stream>>>(scrF, rel, l, oH);
        // attn output projection + residual -> scrF (h1pre)
        gemm_kernel<64><<<dim3(12, 32), 256, 0, stream>>>(
            oH, BTwo + (size_t)l * 768 * 256, nullptr, resIn, scrF, nullptr,
            M_, 768, 256, 2 | 8, 768, 768);
        ln_kernel<<<M_, 256, 0, stream>>>(scrF, ln1w + l * 768, ln1b + l * 768, ln1F, ln1H);
        // FFN1: ReLU(ln1 @ lin1^T + b1) -> ffH (f16 only)
        gemm_kernel<128><<<dim3(24, 32), 256, 0, stream>>>(
            ln1H, lin1H + (size_t)l * 3072 * 768, lin1b + l * 3072, nullptr, nullptr, ffH,
            M_, 3072, 768, 1 | 4 | 16, 3072, 3072);
        // FFN2: ff @ lin2^T + b2 + ln1 residual -> scrF (h2pre)
        gemm_kernel<64><<<dim3(12, 32), 256, 0, stream>>>(
            ffH, lin2H + (size_t)l * 768 * 3072, lin2b + l * 768, ln1F, scrF, nullptr,
            M_, 768, 3072, 1 | 2 | 8, 768, 768);
        ln_kernel<<<M_, 256, 0, stream>>>(scrF, ln2w + l * 768, ln2b + l * 768, hF, hH);
    }
    // final projection via MFMA GEMM (w_out zero-padded to 128 rows)
    gemm_kernel<64><<<dim3(2, 32), 256, 0, stream>>>(
        hH, woutH, bout, nullptr, (float*)d_out, nullptr,
        M_, 80, 768, 1 | 8, 80, 80);
}

// Round 3
// 1025.721 us; speedup vs baseline: 1.1446x; 1.1393x over previous
//
#include <hip/hip_runtime.h>

typedef _Float16 f16;
typedef f16 f16x8 __attribute__((ext_vector_type(8)));
typedef f16 f16x4 __attribute__((ext_vector_type(4)));
typedef float f32x4 __attribute__((ext_vector_type(4)));

#define B_ 4
#define T_ 512
#define DM_ 768
#define H_ 8
#define DQ_ 32
#define FF_ 3072
#define L_ 6
#define OUT_ 80
#define M_ (B_*T_)   // 2048 tokens

// ---------------- conversion / packing kernels (run every launch; ws is poisoned) ----------------

__global__ void cast4_kernel(const float* __restrict__ in, f16* __restrict__ out, int n4) {
    int id = blockIdx.x * 256 + threadIdx.x;
    if (id < n4) {
        const float4 v = ((const float4*)in)[id];
        f16x4 o; o[0] = (f16)v.x; o[1] = (f16)v.y; o[2] = (f16)v.z; o[3] = (f16)v.w;
        ((f16x4*)out)[id] = o;
    }
}

// BTqkv[l][n][k], n in [0,768): n<256 -> wq (scaled), 256..511 -> wk, 512..767 -> wv
__global__ void pack_qkv_kernel(const float* __restrict__ wq, const float* __restrict__ wk,
                                const float* __restrict__ wv, f16* __restrict__ out) {
    long id = (long)blockIdx.x * 256 + threadIdx.x;
    if (id >= (long)L_ * 768 * 768) return;
    int k = (int)(id % 768);
    long t = id / 768;
    int n = (int)(t % 768);
    int l = (int)(t / 768);
    int sec = n >> 8; int nn = n & 255; int h = nn >> 5; int a = nn & 31;
    const float* w = (sec == 0) ? wq : (sec == 1 ? wk : wv);
    float v = w[(((long)l * H_ + h) * DM_ + k) * DQ_ + a];
    if (sec == 0) v *= 0.17677669529663687f;   // 1/sqrt(DQ) folded into q weights
    out[id] = (f16)v;
}

// BTwo[l][n=dm][k=f], f = h*32+a ; wo layout (L,H,DQ,DM)
__global__ void pack_wo_kernel(const float* __restrict__ wo, f16* __restrict__ out) {
    long id = (long)blockIdx.x * 256 + threadIdx.x;
    if (id >= (long)L_ * 768 * 256) return;
    int k = (int)(id % 256);
    long t = id / 256;
    int n = (int)(t % 768);
    int l = (int)(t / 768);
    int h = k >> 5, a = k & 31;
    out[id] = (f16)wo[(((long)l * H_ + h) * DQ_ + a) * DM_ + n];
}

// w_out (80,768) -> f16 zero-padded to (128,768)
__global__ void pack_wout_kernel(const float* __restrict__ wout, f16* __restrict__ out) {
    int id = blockIdx.x * 256 + threadIdx.x;
    if (id >= 128 * 768) return;
    int k = id % 768, n = id / 768;
    out[id] = (n < OUT_) ? (f16)wout[n * 768 + k] : (f16)0;
}

// relH[l][h][208][32] f16, rows d>=199 zero
__global__ void pack_rel_kernel(const float* __restrict__ rel, f16* __restrict__ out) {
    int id = blockIdx.x * 256 + threadIdx.x;
    if (id >= L_ * 8 * 208 * 32) return;
    int a = id & 31;
    int t = id >> 5;
    int d = t % 208;
    int lh = t / 208;
    out[id] = (d < 199) ? (f16)rel[((long)lh * 199 + d) * 32 + a] : (f16)0;
}

// ---------------- GEMM: C[M,N] = A[M,K] @ Bt[N,K]^T, f16 in, fp32 acc ----------------
// mode bits: 1=+bias[col], 2=+res[row,col] (fp32, stride N), 4=ReLU, 8=write outF, 16=write outH,
//            32=qkv special epilogue (cols<512 -> outH[row*512+col], cols>=512 -> vT transposed)

template<int BM, int BN>
__global__ __launch_bounds__(256) void gemm_kernel(
    const f16* __restrict__ A, const f16* __restrict__ Bt,
    const float* __restrict__ bias, const float* __restrict__ res,
    float* __restrict__ outF, f16* __restrict__ outH, f16* __restrict__ vTout,
    int M, int N, int K, int mode, int ldOut, int nMax)
{
    constexpr int IA = BM / 32;   // A frags per wave (rows)
    constexpr int JF = BN / 32;   // B frags per wave (cols)
    constexpr int NA = BM / 64;   // 64-row staging chunks
    constexpr int NB = BN / 64;
    __shared__ __align__(16) f16 As[BM * 40];
    __shared__ __align__(16) f16 Bs[BN * 40];
    const int tid = threadIdx.x;
    const int m0 = blockIdx.y * BM, n0 = blockIdx.x * BN;
    const int wave = tid >> 6, lane = tid & 63;
    const int wr = wave >> 1, wc = wave & 1;
    const int l15 = lane & 15, l4 = lane >> 4;
    const int sr = tid >> 2, sc = (tid & 3) * 8;

    const f16* Ap[NA];
    const f16* Bp[NB];
#pragma unroll
    for (int t = 0; t < NA; ++t) Ap[t] = A + (long)(m0 + sr + 64 * t) * K + sc;
#pragma unroll
    for (int t = 0; t < NB; ++t) Bp[t] = Bt + (long)(n0 + sr + 64 * t) * K + sc;

    f32x4 acc[IA][JF];
#pragma unroll
    for (int i = 0; i < IA; ++i)
#pragma unroll
        for (int j = 0; j < JF; ++j) acc[i][j] = (f32x4){0.f, 0.f, 0.f, 0.f};

    uint4 av[NA], bv[NB];
#pragma unroll
    for (int t = 0; t < NA; ++t) av[t] = *(const uint4*)Ap[t];
#pragma unroll
    for (int t = 0; t < NB; ++t) bv[t] = *(const uint4*)Bp[t];

    for (int k0 = 0; k0 < K; k0 += 32) {
#pragma unroll
        for (int t = 0; t < NA; ++t) *(uint4*)(&As[(sr + 64 * t) * 40 + sc]) = av[t];
#pragma unroll
        for (int t = 0; t < NB; ++t) *(uint4*)(&Bs[(sr + 64 * t) * 40 + sc]) = bv[t];
        __syncthreads();
        if (k0 + 32 < K) {
#pragma unroll
            for (int t = 0; t < NA; ++t) av[t] = *(const uint4*)(Ap[t] + k0 + 32);
#pragma unroll
            for (int t = 0; t < NB; ++t) bv[t] = *(const uint4*)(Bp[t] + k0 + 32);
        }
        f16x8 af[IA], bf[JF];
#pragma unroll
        for (int i = 0; i < IA; ++i)
            af[i] = *(const f16x8*)(&As[(wr * (BM / 2) + i * 16 + l15) * 40 + l4 * 8]);
#pragma unroll
        for (int j = 0; j < JF; ++j)
            bf[j] = *(const f16x8*)(&Bs[(wc * (BN / 2) + j * 16 + l15) * 40 + l4 * 8]);
#pragma unroll
        for (int i = 0; i < IA; ++i)
#pragma unroll
            for (int j = 0; j < JF; ++j)
                acc[i][j] = __builtin_amdgcn_mfma_f32_16x16x32_f16(af[i], bf[j], acc[i][j], 0, 0, 0);
        __syncthreads();
    }

#pragma unroll
    for (int i = 0; i < IA; ++i) {
#pragma unroll
        for (int j = 0; j < JF; ++j) {
            const int col = n0 + wc * (BN / 2) + j * 16 + l15;
            if (mode & 32) {
#pragma unroll
                for (int r = 0; r < 4; ++r) {
                    const int row = m0 + wr * (BM / 2) + i * 16 + l4 * 4 + r;
                    float v = acc[i][j][r];
                    if (col < 512) {
                        outH[(long)row * 512 + col] = (f16)v;
                    } else {
                        const int bb = row >> 9, t = row & 511;
                        vTout[((long)(bb * 256 + (col - 512))) * 512 + t] = (f16)v;
                    }
                }
            } else if (col < nMax) {
                const float bvv = (mode & 1) ? bias[col] : 0.f;
#pragma unroll
                for (int r = 0; r < 4; ++r) {
                    const int row = m0 + wr * (BM / 2) + i * 16 + l4 * 4 + r;
                    float v = acc[i][j][r] + bvv;
                    if (mode & 2) v += res[(long)row * N + col];
                    if (mode & 4) v = fmaxf(v, 0.f);
                    if (mode & 8)  outF[(long)row * ldOut + col] = v;
                    if (mode & 16) outH[(long)row * ldOut + col] = (f16)v;
                }
            }
        }
    }
}

// ---------------- banded attention via MFMA ----------------
// qkvH [2048][512] f16 = q|k (q pre-scaled); vT [4][256][512] f16; relH [L][8][208][32] f16.
// band: logits finite only for |k-q| <= 99; out-of-band prob == 0 exactly.
// grid (8 qtiles, 8 heads, 4 batch), 256 threads = 4 waves, wave w owns q-rows [16w,16w+16).

__global__ __launch_bounds__(256) void attn_kernel(
    const f16* __restrict__ qkvH, const f16* __restrict__ vT,
    const f16* __restrict__ relH, int l, f16* __restrict__ o)
{
    __shared__ __align__(16) f16 Qs[64 * 40];
    __shared__ __align__(16) f16 Ks[288 * 40];
    __shared__ __align__(16) f16 Vt[32 * 296];
    __shared__ __align__(16) f16 Ps[64 * 296];
    __shared__ __align__(16) f16 Rl[64 * 216];
    const int tid = threadIdx.x;
    const int qb = blockIdx.x, h = blockIdx.y, b = blockIdx.z;
    const int q0 = qb * 64;
    const int lo = max(0, q0 - 99);
    const int hi = min(512, q0 + 163);
    const int nk = hi - lo;

    // stage Q (64x32)
    {
        const int r = tid >> 2, c = tid & 3;
        *(f16x8*)&Qs[r * 40 + c * 8] =
            *(const f16x8*)(qkvH + ((long)(b * 512 + q0 + r)) * 512 + h * 32 + c * 8);
    }
    // stage K window zero-padded to 288 rows
    for (int idx = tid; idx < 288 * 4; idx += 256) {
        const int r = idx >> 2, c = idx & 3;
        f16x8 v = {};
        if (r < nk)
            v = *(const f16x8*)(qkvH + ((long)(b * 512 + lo + r)) * 512 + 256 + h * 32 + c * 8);
        *(f16x8*)&Ks[r * 40 + c * 8] = v;
    }
    // stage V^T (32 x 288), scalar loads (window start may be misaligned)
    for (int idx = tid; idx < 32 * 288; idx += 256) {
        const int a = idx / 288, kk = idx % 288;
        f16 v = (f16)0;
        if (kk < nk) v = vT[((long)(b * 256 + h * 32 + a)) * 512 + lo + kk];
        Vt[a * 296 + kk] = v;
    }
    __syncthreads();

    const int wave = tid >> 6, lane = tid & 63;
    const int l15 = lane & 15, l4 = lane >> 4;
    const int qloc = wave * 16;

    const f16x8 qf = *(const f16x8*)&Qs[(qloc + l15) * 40 + l4 * 8];

    // rel logits rl[q][d] = q . rel[d]  (13 frags cover d in [0,208))
    const f16* relh = relH + ((long)(l * 8 + h)) * 208 * 32;
    {
        f32x4 racc[13];
#pragma unroll
        for (int fd = 0; fd < 13; ++fd) {
            const f16x8 bf = *(const f16x8*)(relh + (fd * 16 + l15) * 32 + l4 * 8);
            racc[fd] = __builtin_amdgcn_mfma_f32_16x16x32_f16(qf, bf, (f32x4){0.f,0.f,0.f,0.f}, 0, 0, 0);
        }
#pragma unroll
        for (int fd = 0; fd < 13; ++fd)
#pragma unroll
            for (int r = 0; r < 4; ++r)
                Rl[(qloc + l4 * 4 + r) * 216 + fd * 16 + l15] = (f16)racc[fd][r];
    }

    // S = Q K^T over padded window (18 frags x 16 cols)
    f32x4 sacc[18];
#pragma unroll
    for (int fk = 0; fk < 18; ++fk) {
        const f16x8 bf = *(const f16x8*)&Ks[(fk * 16 + l15) * 40 + l4 * 8];
        sacc[fk] = __builtin_amdgcn_mfma_f32_16x16x32_f16(qf, bf, (f32x4){0.f,0.f,0.f,0.f}, 0, 0, 0);
    }

    // band-add rel logits + mask; row max
    float mx[4] = {-1e30f, -1e30f, -1e30f, -1e30f};
#pragma unroll
    for (int fk = 0; fk < 18; ++fk) {
        const int kk = fk * 16 + l15;
        const int k = lo + kk;
#pragma unroll
        for (int r = 0; r < 4; ++r) {
            const int q = q0 + qloc + l4 * 4 + r;
            const int d = k - q + 99;
            float v = -1e30f;
            if (kk < nk && d >= 0 && d < 199)
                v = sacc[fk][r] + (float)Rl[(qloc + l4 * 4 + r) * 216 + d];
            sacc[fk][r] = v;
            mx[r] = fmaxf(mx[r], v);
        }
    }
#pragma unroll
    for (int r = 0; r < 4; ++r) {
        mx[r] = fmaxf(mx[r], __shfl_xor(mx[r], 1));
        mx[r] = fmaxf(mx[r], __shfl_xor(mx[r], 2));
        mx[r] = fmaxf(mx[r], __shfl_xor(mx[r], 4));
        mx[r] = fmaxf(mx[r], __shfl_xor(mx[r], 8));
    }
    float sum[4] = {0.f, 0.f, 0.f, 0.f};
#pragma unroll
    for (int fk = 0; fk < 18; ++fk) {
        const int kk = fk * 16 + l15;
#pragma unroll
        for (int r = 0; r < 4; ++r) {
            const float p = __expf(sacc[fk][r] - mx[r]);   // invalid -> exp(-huge) == 0
            sum[r] += p;
            Ps[(qloc + l4 * 4 + r) * 296 + kk] = (f16)p;
        }
    }
#pragma unroll
    for (int r = 0; r < 4; ++r) {
        sum[r] += __shfl_xor(sum[r], 1);
        sum[r] += __shfl_xor(sum[r], 2);
        sum[r] += __shfl_xor(sum[r], 4);
        sum[r] += __shfl_xor(sum[r], 8);
    }

    // O = P V  (wave reads only its own Ps rows; no barrier needed)
    f32x4 oacc[2] = {{0.f,0.f,0.f,0.f}, {0.f,0.f,0.f,0.f}};
#pragma unroll
    for (int ks = 0; ks < 9; ++ks) {
        const f16x8 pa = *(const f16x8*)&Ps[(qloc + l15) * 296 + ks * 32 + l4 * 8];
#pragma unroll
        for (int j = 0; j < 2; ++j) {
            const f16x8 vb = *(const f16x8*)&Vt[(j * 16 + l15) * 296 + ks * 32 + l4 * 8];
            oacc[j] = __builtin_amdgcn_mfma_f32_16x16x32_f16(pa, vb, oacc[j], 0, 0, 0);
        }
    }

    f16* ob = o + ((long)(b * 512 + q0 + qloc + l4 * 4)) * 256 + h * 32;
#pragma unroll
    for (int r = 0; r < 4; ++r) {
        const float inv = 1.f / sum[r];
#pragma unroll
        for (int j = 0; j < 2; ++j)
            ob[(long)r * 256 + j * 16 + l15] = (f16)(oacc[j][r] * inv);
    }
}

// ---------------- LayerNorm over 768, writes fp32 (residual) + f16 (next GEMM A) ----------------

__global__ __launch_bounds__(256) void ln_kernel(
    const float* __restrict__ src, const float* __restrict__ w, const float* __restrict__ bb,
    float* __restrict__ outF, f16* __restrict__ outH)
{
    __shared__ float red1[4], red2[4];
    const int row = blockIdx.x, tid = threadIdx.x;
    const float* x = src + (long)row * 768;
    float v0 = x[tid], v1 = x[tid + 256], v2 = x[tid + 512];
    float s = v0 + v1 + v2;
#pragma unroll
    for (int off = 32; off > 0; off >>= 1) s += __shfl_xor(s, off);
    if ((tid & 63) == 0) red1[tid >> 6] = s;
    __syncthreads();
    const float mu = (red1[0] + red1[1] + red1[2] + red1[3]) * (1.f / 768.f);
    const float d0 = v0 - mu, d1 = v1 - mu, d2 = v2 - mu;
    float ss = d0 * d0 + d1 * d1 + d2 * d2;
#pragma unroll
    for (int off = 32; off > 0; off >>= 1) ss += __shfl_xor(ss, off);
    if ((tid & 63) == 0) red2[tid >> 6] = ss;
    __syncthreads();
    const float var = (red2[0] + red2[1] + red2[2] + red2[3]) * (1.f / 768.f);
    const float inv = rsqrtf(var + 1e-5f);
    float y0 = d0 * inv * w[tid]       + bb[tid];
    float y1 = d1 * inv * w[tid + 256] + bb[tid + 256];
    float y2 = d2 * inv * w[tid + 512] + bb[tid + 512];
    long base = (long)row * 768;
    outF[base + tid] = y0; outF[base + tid + 256] = y1; outF[base + tid + 512] = y2;
    outH[base + tid] = (f16)y0; outH[base + tid + 256] = (f16)y1; outH[base + tid + 512] = (f16)y2;
}

// ---------------- host ----------------

extern "C" void kernel_launch(void* const* d_in, const int* in_sizes, int n_in,
                              void* d_out, int out_size, void* d_ws, size_t ws_size,
                              hipStream_t stream) {
    const float* x     = (const float*)d_in[0];
    const float* wq    = (const float*)d_in[1];
    const float* wk    = (const float*)d_in[2];
    const float* wv    = (const float*)d_in[3];
    const float* wo    = (const float*)d_in[4];
    const float* rel   = (const float*)d_in[5];
    const float* lin1w = (const float*)d_in[6];
    const float* lin1b = (const float*)d_in[7];
    const float* lin2w = (const float*)d_in[8];
    const float* lin2b = (const float*)d_in[9];
    const float* ln1w  = (const float*)d_in[10];
    const float* ln1b  = (const float*)d_in[11];
    const float* ln2w  = (const float*)d_in[12];
    const float* ln2b  = (const float*)d_in[13];
    const float* wout  = (const float*)d_in[14];
    const float* bout  = (const float*)d_in[15];

    char* base = (char*)d_ws;
    size_t off = 0;
    auto alloc = [&](size_t bytes) {
        void* p = base + off;
        off = (off + bytes + 255) & ~(size_t)255;
        return p;
    };
    f16*   xH    = (f16*)  alloc((size_t)M_ * 768 * 2);
    f16*   BTqkv = (f16*)  alloc((size_t)L_ * 768 * 768 * 2);
    f16*   BTwo  = (f16*)  alloc((size_t)L_ * 768 * 256 * 2);
    f16*   lin1H = (f16*)  alloc((size_t)L_ * 3072 * 768 * 2);
    f16*   lin2H = (f16*)  alloc((size_t)L_ * 768 * 3072 * 2);
    f16*   woutH = (f16*)  alloc((size_t)128 * 768 * 2);
    f16*   relH  = (f16*)  alloc((size_t)L_ * 8 * 208 * 32 * 2);
    f16*   qkvH  = (f16*)  alloc((size_t)M_ * 512 * 2);   // q|k
    f16*   vTbuf = (f16*)  alloc((size_t)B_ * 256 * 512 * 2);
    float* scrF  = (float*)alloc((size_t)M_ * 768 * 4);   // h1pre -> h2pre
    f16*   oH    = (f16*)  alloc((size_t)M_ * 256 * 2);
    float* ln1F  = (float*)alloc((size_t)M_ * 768 * 4);
    f16*   ln1H  = (f16*)  alloc((size_t)M_ * 768 * 2);
    f16*   ffH   = (f16*)  alloc((size_t)M_ * 3072 * 2);
    float* hF    = (float*)alloc((size_t)M_ * 768 * 4);
    f16*   hH    = (f16*)  alloc((size_t)M_ * 768 * 2);
    (void)ws_size; (void)in_sizes; (void)n_in; (void)out_size;

    cast4_kernel<<<(M_ * 768 / 4 + 255) / 256, 256, 0, stream>>>(x, xH, M_ * 768 / 4);
    cast4_kernel<<<(L_ * 3072 * 768 / 4 + 255) / 256, 256, 0, stream>>>(lin1w, lin1H, L_ * 3072 * 768 / 4);
    cast4_kernel<<<(L_ * 768 * 3072 / 4 + 255) / 256, 256, 0, stream>>>(lin2w, lin2H, L_ * 768 * 3072 / 4);
    pack_qkv_kernel<<<(L_ * 768 * 768 + 255) / 256, 256, 0, stream>>>(wq, wk, wv, BTqkv);
    pack_wo_kernel<<<(L_ * 768 * 256 + 255) / 256, 256, 0, stream>>>(wo, BTwo);
    pack_wout_kernel<<<(128 * 768 + 255) / 256, 256, 0, stream>>>(wout, woutH);
    pack_rel_kernel<<<(L_ * 8 * 208 * 32 + 255) / 256, 256, 0, stream>>>(rel, relH);

    for (int l = 0; l < L_; ++l) {
        const f16*   aIn   = (l == 0) ? xH : hH;
        const float* resIn = (l == 0) ? x  : hF;
        // QKV projection -> qkvH (q|k, f16) + vTbuf (V transposed, f16)
        gemm_kernel<64, 64><<<dim3(12, 32), 256, 0, stream>>>(
            aIn, BTqkv + (size_t)l * 768 * 768, nullptr, nullptr, nullptr, qkvH, vTbuf,
            M_, 768, 768, 32, 512, 768);
        // banded MFMA attention -> oH (b,t,256) f16
        attn_kernel<<<dim3(8, 8, 4), 256, 0, stream>>>(qkvH, vTbuf, relH, l, oH);
        // attn output projection + residual -> scrF (h1pre)
        gemm_kernel<64, 64><<<dim3(12, 32), 256, 0, stream>>>(
            oH, BTwo + (size_t)l * 768 * 256, nullptr, resIn, scrF, nullptr, nullptr,
            M_, 768, 256, 2 | 8, 768, 768);
        ln_kernel<<<M_, 256, 0, stream>>>(scrF, ln1w + l * 768, ln1b + l * 768, ln1F, ln1H);
        // FFN1: ReLU(ln1 @ lin1^T + b1) -> ffH (f16), 128x128 tile
        gemm_kernel<128, 128><<<dim3(24, 16), 256, 0, stream>>>(
            ln1H, lin1H + (size_t)l * 3072 * 768, lin1b + l * 3072, nullptr, nullptr, ffH, nullptr,
            M_, 3072, 768, 1 | 4 | 16, 3072, 3072);
        // FFN2: ff @ lin2^T + b2 + ln1 residual -> scrF (h2pre)
        gemm_kernel<64, 64><<<dim3(12, 32), 256, 0, stream>>>(
            ffH, lin2H + (size_t)l * 768 * 3072, lin2b + l * 768, ln1F, scrF, nullptr, nullptr,
            M_, 768, 3072, 1 | 2 | 8, 768, 768);
        ln_kernel<<<M_, 256, 0, stream>>>(scrF, ln2w + l * 768, ln2b + l * 768, hF, hH);
    }
    // final projection via MFMA GEMM (w_out zero-padded to 128 rows)
    gemm_kernel<64, 64><<<dim3(2, 32), 256, 0, stream>>>(
        hH, woutH, bout, nullptr, (float*)d_out, nullptr, nullptr,
        M_, 80, 768, 1 | 8, 80, 80);
}

// Round 4
// 718.433 us; speedup vs baseline: 1.6341x; 1.4277x over previous
//
#include <hip/hip_runtime.h>

typedef _Float16 f16;
typedef f16 f16x8 __attribute__((ext_vector_type(8)));
typedef f16 f16x4 __attribute__((ext_vector_type(4)));
typedef float f32x4 __attribute__((ext_vector_type(4)));

#define B_ 4
#define T_ 512
#define DM_ 768
#define H_ 8
#define DQ_ 32
#define FF_ 3072
#define L_ 6
#define OUT_ 80
#define M_ (B_*T_)   // 2048 tokens

// async global->LDS, 16B per lane; LDS dest is wave-uniform base + lane*16
__device__ __forceinline__ void gload16(const f16* g, f16* l) {
    __builtin_amdgcn_global_load_lds(
        (const __attribute__((address_space(1))) unsigned int*)g,
        (__attribute__((address_space(3))) unsigned int*)l, 16, 0, 0);
}

// ---------------- conversion / packing kernels (run every launch; ws is poisoned) ----------------

__global__ void cast4_kernel(const float* __restrict__ in, f16* __restrict__ out, int n4) {
    int id = blockIdx.x * 256 + threadIdx.x;
    if (id < n4) {
        const float4 v = ((const float4*)in)[id];
        f16x4 o; o[0] = (f16)v.x; o[1] = (f16)v.y; o[2] = (f16)v.z; o[3] = (f16)v.w;
        ((f16x4*)out)[id] = o;
    }
}

// BTqkv[l][n][k], n in [0,768): n<256 -> wq (scaled), 256..511 -> wk, 512..767 -> wv
__global__ void pack_qkv_kernel(const float* __restrict__ wq, const float* __restrict__ wk,
                                const float* __restrict__ wv, f16* __restrict__ out) {
    long id = (long)blockIdx.x * 256 + threadIdx.x;
    if (id >= (long)L_ * 768 * 768) return;
    int k = (int)(id % 768);
    long t = id / 768;
    int n = (int)(t % 768);
    int l = (int)(t / 768);
    int sec = n >> 8; int nn = n & 255; int h = nn >> 5; int a = nn & 31;
    const float* w = (sec == 0) ? wq : (sec == 1 ? wk : wv);
    float v = w[(((long)l * H_ + h) * DM_ + k) * DQ_ + a];
    if (sec == 0) v *= 0.17677669529663687f;   // 1/sqrt(DQ) folded into q weights
    out[id] = (f16)v;
}

// BTwo[l][n=dm][k=f], f = h*32+a ; wo layout (L,H,DQ,DM)
__global__ void pack_wo_kernel(const float* __restrict__ wo, f16* __restrict__ out) {
    long id = (long)blockIdx.x * 256 + threadIdx.x;
    if (id >= (long)L_ * 768 * 256) return;
    int k = (int)(id % 256);
    long t = id / 256;
    int n = (int)(t % 768);
    int l = (int)(t / 256 / 768);
    l = (int)(t / (256 * 3));   // unused; recompute below properly
    // recompute cleanly
    long t2 = id / 256;
    n = (int)(t2 % 768);
    l = (int)(t2 / 768);
    int h = k >> 5, a = k & 31;
    out[id] = (f16)wo[(((long)l * H_ + h) * DQ_ + a) * DM_ + n];
}

// w_out (80,768) -> f16 zero-padded to (128,768)
__global__ void pack_wout_kernel(const float* __restrict__ wout, f16* __restrict__ out) {
    int id = blockIdx.x * 256 + threadIdx.x;
    if (id >= 128 * 768) return;
    int k = id % 768, n = id / 768;
    out[id] = (n < OUT_) ? (f16)wout[n * 768 + k] : (f16)0;
}

// relH[l][h][208][32] f16, rows d>=199 zero
__global__ void pack_rel_kernel(const float* __restrict__ rel, f16* __restrict__ out) {
    int id = blockIdx.x * 256 + threadIdx.x;
    if (id >= L_ * 8 * 208 * 32) return;
    int a = id & 31;
    int t = id >> 5;
    int d = t % 208;
    int lh = t / 208;
    out[id] = (d < 199) ? (f16)rel[((long)lh * 199 + d) * 32 + a] : (f16)0;
}

// ---------------- GEMM (m97-style): C[M,N] = A[M,K] @ Bt[N,K]^T, f16 in, fp32 acc ----------------
// global_load_lds width-16 staging into linear LDS, BK=64, 2 barriers per K-step.
// mode bits: 1=+bias[col], 2=+res[row,col] (fp32, stride N), 4=ReLU, 8=write outF, 16=write outH,
//            32=qkv epilogue (cols<512 -> qkvH, cols>=512 -> vT transposed), 64=split-K partial

template<int BM, int BN>
__global__ __launch_bounds__(256) void gemm2_kernel(
    const f16* __restrict__ A, const f16* __restrict__ Bt,
    const float* __restrict__ bias, const float* __restrict__ res,
    float* __restrict__ outF, f16* __restrict__ outH, f16* __restrict__ vTout,
    int M, int N, int K, int mode, int ldOut, int nMax)
{
    constexpr int IA = BM / 32;     // A frags per wave
    constexpr int JF = BN / 32;     // B frags per wave
    constexpr int CA = BM / 8;      // 1KB staging chunks (8 rows x 128B)
    constexpr int CB = BN / 8;
    __shared__ __align__(16) f16 As[BM * 64];
    __shared__ __align__(16) f16 Bs[BN * 64];
    const int tid = threadIdx.x;
    const int wave = tid >> 6, lane = tid & 63;
    const int m0 = blockIdx.y * BM, n0 = blockIdx.x * BN;
    const int z = blockIdx.z;
    const int Kl = K / (int)gridDim.z;
    const int kb = z * Kl;
    const int wr = wave >> 1, wc = wave & 1;
    const int l15 = lane & 15, l4 = lane >> 4;
    const int lrow = lane >> 3, lcol = (lane & 7) * 8;   // staging lane mapping

    const f16* Abase = A  + (long)(m0 + lrow) * K + kb + lcol;
    const f16* Bbase = Bt + (long)(n0 + lrow) * K + kb + lcol;

    f32x4 acc[IA][JF];
#pragma unroll
    for (int i = 0; i < IA; ++i)
#pragma unroll
        for (int j = 0; j < JF; ++j) acc[i][j] = (f32x4){0.f, 0.f, 0.f, 0.f};

    for (int k0 = 0; k0 < Kl; k0 += 64) {
#pragma unroll
        for (int i = 0; i < CA / 4; ++i) {
            const int c = wave + 4 * i;
            gload16(Abase + (long)c * 8 * K + k0, &As[c * 512]);
        }
#pragma unroll
        for (int i = 0; i < CB / 4; ++i) {
            const int c = wave + 4 * i;
            gload16(Bbase + (long)c * 8 * K + k0, &Bs[c * 512]);
        }
        __syncthreads();   // drains vmcnt -> staged tile visible
#pragma unroll
        for (int s = 0; s < 2; ++s) {
            f16x8 af[IA], bf[JF];
#pragma unroll
            for (int i = 0; i < IA; ++i)
                af[i] = *(const f16x8*)&As[(wr * (BM / 2) + i * 16 + l15) * 64 + s * 32 + l4 * 8];
#pragma unroll
            for (int j = 0; j < JF; ++j)
                bf[j] = *(const f16x8*)&Bs[(wc * (BN / 2) + j * 16 + l15) * 64 + s * 32 + l4 * 8];
#pragma unroll
            for (int i = 0; i < IA; ++i)
#pragma unroll
                for (int j = 0; j < JF; ++j)
                    acc[i][j] = __builtin_amdgcn_mfma_f32_16x16x32_f16(af[i], bf[j], acc[i][j], 0, 0, 0);
        }
        __syncthreads();
    }

#pragma unroll
    for (int i = 0; i < IA; ++i) {
#pragma unroll
        for (int j = 0; j < JF; ++j) {
            const int col = n0 + wc * (BN / 2) + j * 16 + l15;
            if (mode & 32) {
#pragma unroll
                for (int r = 0; r < 4; ++r) {
                    const int row = m0 + wr * (BM / 2) + i * 16 + l4 * 4 + r;
                    float v = acc[i][j][r];
                    if (col < 512) {
                        outH[(long)row * 512 + col] = (f16)v;
                    } else {
                        const int bb = row >> 9, t = row & 511;
                        vTout[((long)(bb * 256 + (col - 512))) * 512 + t] = (f16)v;
                    }
                }
            } else if (mode & 64) {
                float* po = outF + (long)z * M * ldOut;
#pragma unroll
                for (int r = 0; r < 4; ++r) {
                    const int row = m0 + wr * (BM / 2) + i * 16 + l4 * 4 + r;
                    po[(long)row * ldOut + col] = acc[i][j][r];
                }
            } else if (col < nMax) {
                const float bvv = (mode & 1) ? bias[col] : 0.f;
#pragma unroll
                for (int r = 0; r < 4; ++r) {
                    const int row = m0 + wr * (BM / 2) + i * 16 + l4 * 4 + r;
                    float v = acc[i][j][r] + bvv;
                    if (mode & 2) v += res[(long)row * N + col];
                    if (mode & 4) v = fmaxf(v, 0.f);
                    if (mode & 8)  outF[(long)row * ldOut + col] = v;
                    if (mode & 16) outH[(long)row * ldOut + col] = (f16)v;
                }
            }
        }
    }
}

// ---------------- banded attention via MFMA ----------------
// qkvH [2048][512] f16 = q|k (q pre-scaled); vT [4][256][512] f16; relH [L][8][208][32] f16.
// band: logits finite only for |k-q| <= 99; out-of-band prob == 0 exactly.
// grid (8 qtiles, 8 heads, 4 batch), 256 threads = 4 waves, wave w owns q-rows [16w,16w+16).

__global__ __launch_bounds__(256) void attn_kernel(
    const f16* __restrict__ qkvH, const f16* __restrict__ vT,
    const f16* __restrict__ relH, int l, f16* __restrict__ o)
{
    __shared__ __align__(16) f16 Qs[64 * 40];
    __shared__ __align__(16) f16 Ks[288 * 40];
    __shared__ __align__(16) f16 Vt[32 * 296];
    __shared__ __align__(16) f16 Ps[64 * 296];
    __shared__ __align__(16) f16 Rl[64 * 216];
    const int tid = threadIdx.x;
    const int qb = blockIdx.x, h = blockIdx.y, b = blockIdx.z;
    const int q0 = qb * 64;
    const int lo = max(0, q0 - 99);
    const int hi = min(512, q0 + 163);
    const int nk = hi - lo;

    // stage Q (64x32)
    {
        const int r = tid >> 2, c = tid & 3;
        *(f16x8*)&Qs[r * 40 + c * 8] =
            *(const f16x8*)(qkvH + ((long)(b * 512 + q0 + r)) * 512 + h * 32 + c * 8);
    }
    // stage K window zero-padded to 288 rows
    for (int idx = tid; idx < 288 * 4; idx += 256) {
        const int r = idx >> 2, c = idx & 3;
        f16x8 v = {};
        if (r < nk)
            v = *(const f16x8*)(qkvH + ((long)(b * 512 + lo + r)) * 512 + 256 + h * 32 + c * 8);
        *(f16x8*)&Ks[r * 40 + c * 8] = v;
    }
    // stage V^T (32 x 288)
    for (int idx = tid; idx < 32 * 288; idx += 256) {
        const int a = idx / 288, kk = idx % 288;
        f16 v = (f16)0;
        if (kk < nk) v = vT[((long)(b * 256 + h * 32 + a)) * 512 + lo + kk];
        Vt[a * 296 + kk] = v;
    }
    __syncthreads();

    const int wave = tid >> 6, lane = tid & 63;
    const int l15 = lane & 15, l4 = lane >> 4;
    const int qloc = wave * 16;

    const f16x8 qf = *(const f16x8*)&Qs[(qloc + l15) * 40 + l4 * 8];

    // rel logits rl[q][d] = q . rel[d]  (13 frags cover d in [0,208))
    const f16* relh = relH + ((long)(l * 8 + h)) * 208 * 32;
    {
        f32x4 racc[13];
#pragma unroll
        for (int fd = 0; fd < 13; ++fd) {
            const f16x8 bf = *(const f16x8*)(relh + (fd * 16 + l15) * 32 + l4 * 8);
            racc[fd] = __builtin_amdgcn_mfma_f32_16x16x32_f16(qf, bf, (f32x4){0.f,0.f,0.f,0.f}, 0, 0, 0);
        }
#pragma unroll
        for (int fd = 0; fd < 13; ++fd)
#pragma unroll
            for (int r = 0; r < 4; ++r)
                Rl[(qloc + l4 * 4 + r) * 216 + fd * 16 + l15] = (f16)racc[fd][r];
    }

    // S = Q K^T over padded window (18 frags x 16 cols)
    f32x4 sacc[18];
#pragma unroll
    for (int fk = 0; fk < 18; ++fk) {
        const f16x8 bf = *(const f16x8*)&Ks[(fk * 16 + l15) * 40 + l4 * 8];
        sacc[fk] = __builtin_amdgcn_mfma_f32_16x16x32_f16(qf, bf, (f32x4){0.f,0.f,0.f,0.f}, 0, 0, 0);
    }

    // band-add rel logits + mask; row max
    float mx[4] = {-1e30f, -1e30f, -1e30f, -1e30f};
#pragma unroll
    for (int fk = 0; fk < 18; ++fk) {
        const int kk = fk * 16 + l15;
        const int k = lo + kk;
#pragma unroll
        for (int r = 0; r < 4; ++r) {
            const int q = q0 + qloc + l4 * 4 + r;
            const int d = k - q + 99;
            float v = -1e30f;
            if (kk < nk && d >= 0 && d < 199)
                v = sacc[fk][r] + (float)Rl[(qloc + l4 * 4 + r) * 216 + d];
            sacc[fk][r] = v;
            mx[r] = fmaxf(mx[r], v);
        }
    }
#pragma unroll
    for (int r = 0; r < 4; ++r) {
        mx[r] = fmaxf(mx[r], __shfl_xor(mx[r], 1));
        mx[r] = fmaxf(mx[r], __shfl_xor(mx[r], 2));
        mx[r] = fmaxf(mx[r], __shfl_xor(mx[r], 4));
        mx[r] = fmaxf(mx[r], __shfl_xor(mx[r], 8));
    }
    float sum[4] = {0.f, 0.f, 0.f, 0.f};
#pragma unroll
    for (int fk = 0; fk < 18; ++fk) {
        const int kk = fk * 16 + l15;
#pragma unroll
        for (int r = 0; r < 4; ++r) {
            const float p = __expf(sacc[fk][r] - mx[r]);   // invalid -> exp(-huge) == 0
            sum[r] += p;
            Ps[(qloc + l4 * 4 + r) * 296 + kk] = (f16)p;
        }
    }
#pragma unroll
    for (int r = 0; r < 4; ++r) {
        sum[r] += __shfl_xor(sum[r], 1);
        sum[r] += __shfl_xor(sum[r], 2);
        sum[r] += __shfl_xor(sum[r], 4);
        sum[r] += __shfl_xor(sum[r], 8);
    }

    // O = P V  (wave reads only its own Ps rows; no barrier needed)
    f32x4 oacc[2] = {{0.f,0.f,0.f,0.f}, {0.f,0.f,0.f,0.f}};
#pragma unroll
    for (int ks = 0; ks < 9; ++ks) {
        const f16x8 pa = *(const f16x8*)&Ps[(qloc + l15) * 296 + ks * 32 + l4 * 8];
#pragma unroll
        for (int j = 0; j < 2; ++j) {
            const f16x8 vb = *(const f16x8*)&Vt[(j * 16 + l15) * 296 + ks * 32 + l4 * 8];
            oacc[j] = __builtin_amdgcn_mfma_f32_16x16x32_f16(pa, vb, oacc[j], 0, 0, 0);
        }
    }

    f16* ob = o + ((long)(b * 512 + q0 + qloc + l4 * 4)) * 256 + h * 32;
#pragma unroll
    for (int r = 0; r < 4; ++r) {
        const float inv = 1.f / sum[r];
#pragma unroll
        for (int j = 0; j < 2; ++j)
            ob[(long)r * 256 + j * 16 + l15] = (f16)(oacc[j][r] * inv);
    }
}

// ---------------- LayerNorm over 768, writes fp32 (residual) + f16 (next GEMM A) ----------------

__global__ __launch_bounds__(256) void ln_kernel(
    const float* __restrict__ src, const float* __restrict__ w, const float* __restrict__ bb,
    float* __restrict__ outF, f16* __restrict__ outH)
{
    __shared__ float red1[4], red2[4];
    const int row = blockIdx.x, tid = threadIdx.x;
    const float* x = src + (long)row * 768;
    float v0 = x[tid], v1 = x[tid + 256], v2 = x[tid + 512];
    float s = v0 + v1 + v2;
#pragma unroll
    for (int off = 32; off > 0; off >>= 1) s += __shfl_xor(s, off);
    if ((tid & 63) == 0) red1[tid >> 6] = s;
    __syncthreads();
    const float mu = (red1[0] + red1[1] + red1[2] + red1[3]) * (1.f / 768.f);
    const float d0 = v0 - mu, d1 = v1 - mu, d2 = v2 - mu;
    float ss = d0 * d0 + d1 * d1 + d2 * d2;
#pragma unroll
    for (int off = 32; off > 0; off >>= 1) ss += __shfl_xor(ss, off);
    if ((tid & 63) == 0) red2[tid >> 6] = ss;
    __syncthreads();
    const float var = (red2[0] + red2[1] + red2[2] + red2[3]) * (1.f / 768.f);
    const float inv = rsqrtf(var + 1e-5f);
    float y0 = d0 * inv * w[tid]       + bb[tid];
    float y1 = d1 * inv * w[tid + 256] + bb[tid + 256];
    float y2 = d2 * inv * w[tid + 512] + bb[tid + 512];
    long base = (long)row * 768;
    outF[base + tid] = y0; outF[base + tid + 256] = y1; outF[base + tid + 512] = y2;
    outH[base + tid] = (f16)y0; outH[base + tid + 256] = (f16)y1; outH[base + tid + 512] = (f16)y2;
}

// ---------------- split-K combine (sum 4 partials + bias + residual) fused with LayerNorm ----------------

__global__ __launch_bounds__(256) void ln_sum4_kernel(
    const float* __restrict__ p,      // [4][M_][768] partials
    const float* __restrict__ bias, const float* __restrict__ res,
    const float* __restrict__ w, const float* __restrict__ bb,
    float* __restrict__ outF, f16* __restrict__ outH)
{
    __shared__ float red1[4], red2[4];
    const int row = blockIdx.x, tid = threadIdx.x;
    const long rb = (long)row * 768;
    float v[3];
#pragma unroll
    for (int i = 0; i < 3; ++i) {
        const int c = tid + i * 256;
        float s = bias[c] + res[rb + c];
#pragma unroll
        for (int zz = 0; zz < 4; ++zz) s += p[((long)zz * M_ + row) * 768 + c];
        v[i] = s;
    }
    float s = v[0] + v[1] + v[2];
#pragma unroll
    for (int off = 32; off > 0; off >>= 1) s += __shfl_xor(s, off);
    if ((tid & 63) == 0) red1[tid >> 6] = s;
    __syncthreads();
    const float mu = (red1[0] + red1[1] + red1[2] + red1[3]) * (1.f / 768.f);
    const float d0 = v[0] - mu, d1 = v[1] - mu, d2 = v[2] - mu;
    float ss = d0 * d0 + d1 * d1 + d2 * d2;
#pragma unroll
    for (int off = 32; off > 0; off >>= 1) ss += __shfl_xor(ss, off);
    if ((tid & 63) == 0) red2[tid >> 6] = ss;
    __syncthreads();
    const float var = (red2[0] + red2[1] + red2[2] + red2[3]) * (1.f / 768.f);
    const float inv = rsqrtf(var + 1e-5f);
    float y0 = d0 * inv * w[tid]       + bb[tid];
    float y1 = d1 * inv * w[tid + 256] + bb[tid + 256];
    float y2 = d2 * inv * w[tid + 512] + bb[tid + 512];
    outF[rb + tid] = y0; outF[rb + tid + 256] = y1; outF[rb + tid + 512] = y2;
    outH[rb + tid] = (f16)y0; outH[rb + tid + 256] = (f16)y1; outH[rb + tid + 512] = (f16)y2;
}

// ---------------- host ----------------

extern "C" void kernel_launch(void* const* d_in, const int* in_sizes, int n_in,
                              void* d_out, int out_size, void* d_ws, size_t ws_size,
                              hipStream_t stream) {
    const float* x     = (const float*)d_in[0];
    const float* wq    = (const float*)d_in[1];
    const float* wk    = (const float*)d_in[2];
    const float* wv    = (const float*)d_in[3];
    const float* wo    = (const float*)d_in[4];
    const float* rel   = (const float*)d_in[5];
    const float* lin1w = (const float*)d_in[6];
    const float* lin1b = (const float*)d_in[7];
    const float* lin2w = (const float*)d_in[8];
    const float* lin2b = (const float*)d_in[9];
    const float* ln1w  = (const float*)d_in[10];
    const float* ln1b  = (const float*)d_in[11];
    const float* ln2w  = (const float*)d_in[12];
    const float* ln2b  = (const float*)d_in[13];
    const float* wout  = (const float*)d_in[14];
    const float* bout  = (const float*)d_in[15];

    char* base = (char*)d_ws;
    size_t off = 0;
    auto alloc = [&](size_t bytes) {
        void* p = base + off;
        off = (off + bytes + 255) & ~(size_t)255;
        return p;
    };
    f16*   xH    = (f16*)  alloc((size_t)M_ * 768 * 2);
    f16*   BTqkv = (f16*)  alloc((size_t)L_ * 768 * 768 * 2);
    f16*   BTwo  = (f16*)  alloc((size_t)L_ * 768 * 256 * 2);
    f16*   lin1H = (f16*)  alloc((size_t)L_ * 3072 * 768 * 2);
    f16*   lin2H = (f16*)  alloc((size_t)L_ * 768 * 3072 * 2);
    f16*   woutH = (f16*)  alloc((size_t)128 * 768 * 2);
    f16*   relH  = (f16*)  alloc((size_t)L_ * 8 * 208 * 32 * 2);
    f16*   qkvH  = (f16*)  alloc((size_t)M_ * 512 * 2);   // q|k
    f16*   vTbuf = (f16*)  alloc((size_t)B_ * 256 * 512 * 2);
    float* scrF  = (float*)alloc((size_t)M_ * 768 * 4);   // h1pre
    float* part  = (float*)alloc((size_t)4 * M_ * 768 * 4);  // FFN2 split-K partials
    f16*   oH    = (f16*)  alloc((size_t)M_ * 256 * 2);
    float* ln1F  = (float*)alloc((size_t)M_ * 768 * 4);
    f16*   ln1H  = (f16*)  alloc((size_t)M_ * 768 * 2);
    f16*   ffH   = (f16*)  alloc((size_t)M_ * 3072 * 2);
    float* hF    = (float*)alloc((size_t)M_ * 768 * 4);
    f16*   hH    = (f16*)  alloc((size_t)M_ * 768 * 2);
    (void)ws_size; (void)in_sizes; (void)n_in; (void)out_size;

    cast4_kernel<<<(M_ * 768 / 4 + 255) / 256, 256, 0, stream>>>(x, xH, M_ * 768 / 4);
    cast4_kernel<<<(L_ * 3072 * 768 / 4 + 255) / 256, 256, 0, stream>>>(lin1w, lin1H, L_ * 3072 * 768 / 4);
    cast4_kernel<<<(L_ * 768 * 3072 / 4 + 255) / 256, 256, 0, stream>>>(lin2w, lin2H, L_ * 768 * 3072 / 4);
    pack_qkv_kernel<<<(L_ * 768 * 768 + 255) / 256, 256, 0, stream>>>(wq, wk, wv, BTqkv);
    pack_wo_kernel<<<(L_ * 768 * 256 + 255) / 256, 256, 0, stream>>>(wo, BTwo);
    pack_wout_kernel<<<(128 * 768 + 255) / 256, 256, 0, stream>>>(wout, woutH);
    pack_rel_kernel<<<(L_ * 8 * 208 * 32 + 255) / 256, 256, 0, stream>>>(rel, relH);

    for (int l = 0; l < L_; ++l) {
        const f16*   aIn   = (l == 0) ? xH : hH;
        const float* resIn = (l == 0) ? x  : hF;
        // QKV projection -> qkvH (q|k, f16) + vTbuf (V transposed, f16)
        gemm2_kernel<64, 64><<<dim3(12, 32, 1), 256, 0, stream>>>(
            aIn, BTqkv + (size_t)l * 768 * 768, nullptr, nullptr, nullptr, qkvH, vTbuf,
            M_, 768, 768, 32, 512, 768);
        // banded MFMA attention -> oH (b,t,256) f16
        attn_kernel<<<dim3(8, 8, 4), 256, 0, stream>>>(qkvH, vTbuf, relH, l, oH);
        // attn output projection + residual -> scrF (h1pre)
        gemm2_kernel<64, 64><<<dim3(12, 32, 1), 256, 0, stream>>>(
            oH, BTwo + (size_t)l * 768 * 256, nullptr, resIn, scrF, nullptr, nullptr,
            M_, 768, 256, 2 | 8, 768, 768);
        ln_kernel<<<M_, 256, 0, stream>>>(scrF, ln1w + l * 768, ln1b + l * 768, ln1F, ln1H);
        // FFN1: ReLU(ln1 @ lin1^T + b1) -> ffH (f16), 64x128 tile, 768 blocks
        gemm2_kernel<64, 128><<<dim3(24, 32, 1), 256, 0, stream>>>(
            ln1H, lin1H + (size_t)l * 3072 * 768, lin1b + l * 3072, nullptr, nullptr, ffH, nullptr,
            M_, 3072, 768, 1 | 4 | 16, 3072, 3072);
        // FFN2 split-K x4 -> part
        gemm2_kernel<64, 64><<<dim3(12, 32, 4), 256, 0, stream>>>(
            ffH, lin2H + (size_t)l * 768 * 3072, nullptr, nullptr, part, nullptr, nullptr,
            M_, 768, 3072, 64, 768, 768);
        // combine + bias + ln1F residual + LayerNorm -> hF/hH
        ln_sum4_kernel<<<M_, 256, 0, stream>>>(part, lin2b + l * 768, ln1F,
                                               ln2w + l * 768, ln2b + l * 768, hF, hH);
    }
    // final projection via MFMA GEMM (w_out zero-padded to 128 rows)
    gemm2_kernel<64, 64><<<dim3(2, 32, 1), 256, 0, stream>>>(
        hH, woutH, bout, nullptr, (float*)d_out, nullptr, nullptr,
        M_, 80, 768, 1 | 8, 80, 80);
}